// Round 1
// baseline (1998.506 us; speedup 1.0000x reference)
//
#include <hip/hip_runtime.h>
#include <math.h>

#define L 1024
#define BSZV 4
#define NH 16
#define DH 64
#define DM 1024
#define SCALEF 0.125f
#define NEGF -1e30f

// ---------------- GEMM: C[M,N] = A[M,K] * B[N,K]^T (all row-major fp32) ----------------
__global__ __launch_bounds__(256) void gemm_nt(const float* __restrict__ A,
                                               const float* __restrict__ B,
                                               float* __restrict__ C,
                                               int M, int N, int K) {
  __shared__ float sA[16][68];
  __shared__ float sB[16][68];
  int t = threadIdx.x;
  int tx = t & 15, ty = t >> 4;
  int m0 = blockIdx.y << 6, n0 = blockIdx.x << 6;
  int lr = t >> 2;          // 0..63 tile row
  int lc = (t & 3) << 2;    // 0,4,8,12 k offset
  const float* Ap = A + (size_t)(m0 + lr) * K + lc;
  const float* Bp = B + (size_t)(n0 + lr) * K + lc;
  float acc[4][4] = {};
  for (int kb = 0; kb < K; kb += 16) {
    float4 a4 = *(const float4*)(Ap + kb);
    float4 b4 = *(const float4*)(Bp + kb);
    sA[lc + 0][lr] = a4.x; sA[lc + 1][lr] = a4.y; sA[lc + 2][lr] = a4.z; sA[lc + 3][lr] = a4.w;
    sB[lc + 0][lr] = b4.x; sB[lc + 1][lr] = b4.y; sB[lc + 2][lr] = b4.z; sB[lc + 3][lr] = b4.w;
    __syncthreads();
#pragma unroll
    for (int k = 0; k < 16; ++k) {
      float4 av = *(const float4*)&sA[k][ty << 2];
      float4 bv = *(const float4*)&sB[k][tx << 2];
      float am[4] = {av.x, av.y, av.z, av.w};
      float bm[4] = {bv.x, bv.y, bv.z, bv.w};
#pragma unroll
      for (int i = 0; i < 4; ++i)
#pragma unroll
        for (int j = 0; j < 4; ++j)
          acc[i][j] = fmaf(am[i], bm[j], acc[i][j]);
    }
    __syncthreads();
  }
#pragma unroll
  for (int i = 0; i < 4; ++i) {
    float4 o = make_float4(acc[i][0], acc[i][1], acc[i][2], acc[i][3]);
    *(float4*)&C[(size_t)(m0 + (ty << 2) + i) * N + n0 + (tx << 2)] = o;
  }
}

// ---------------- per-head conv1d, k=7, same padding ----------------
// in: [L, BSZ, 1024] (col = n*64 + d_in), out: [L, BSZ, NH, DH]
__global__ __launch_bounds__(256) void conv_head(const float* __restrict__ in,
                                                 const float* __restrict__ wgt,  // [64,64,7]
                                                 const float* __restrict__ bias, // [64]
                                                 float* __restrict__ out) {
  __shared__ float sIn[70][65];
  int t = threadIdx.x;
  int l0 = blockIdx.x << 6;
  int bn = blockIdx.y;
  int b = bn >> 4, n = bn & 15;
  for (int idx = t; idx < 70 * 64; idx += 256) {
    int d = idx & 63, lo = idx >> 6;
    int l = l0 - 3 + lo;
    float v = 0.f;
    if (l >= 0 && l < L) v = in[((size_t)l * BSZV + b) * 1024 + n * 64 + d];
    sIn[lo][d] = v;
  }
  __syncthreads();
  int dout = t & 63, lg = t >> 6;
  float bv = bias[dout];
  float acc[16];
#pragma unroll
  for (int i = 0; i < 16; ++i) acc[i] = bv;
  const float* wp0 = wgt + dout * 64 * 7;
  for (int din = 0; din < 64; ++din) {
    const float* wp = wp0 + din * 7;
    float w0 = wp[0], w1 = wp[1], w2 = wp[2], w3 = wp[3], w4 = wp[4], w5 = wp[5], w6 = wp[6];
#pragma unroll
    for (int li = 0; li < 16; ++li) {
      int ll = lg * 16 + li;
      float s = acc[li];
      s = fmaf(w0, sIn[ll + 0][din], s);
      s = fmaf(w1, sIn[ll + 1][din], s);
      s = fmaf(w2, sIn[ll + 2][din], s);
      s = fmaf(w3, sIn[ll + 3][din], s);
      s = fmaf(w4, sIn[ll + 4][din], s);
      s = fmaf(w5, sIn[ll + 5][din], s);
      s = fmaf(w6, sIn[ll + 6][din], s);
      acc[li] = s;
    }
  }
#pragma unroll
  for (int li = 0; li < 16; ++li) {
    int ll = lg * 16 + li;
    out[(((size_t)(l0 + ll) * BSZV + b) * NH + n) * 64 + dout] = acc[li];
  }
}

// ---------------- fused rel-pos flash attention ----------------
// qh/kh/vh: [L, BSZ, NH, DH]; rhk: [L, 1024]; out vec: [L, BSZ, 1024]
// score(i,j) = (q_i·k_j + rwb·k_j + q_i·r_m + rrb·r_m) * SCALE, m = L-1-i+j, j <= i
__global__ __launch_bounds__(256) void rel_attn(const float* __restrict__ qh,
                                                const float* __restrict__ kh,
                                                const float* __restrict__ vh,
                                                const float* __restrict__ rhk,
                                                const float* __restrict__ rwb_,
                                                const float* __restrict__ rrb_,
                                                float* __restrict__ vec) {
  __shared__ float4 sK[32][17];
  __shared__ float4 sV[32][17];
  __shared__ float4 sR[95][17];
  __shared__ float bk[32];
  __shared__ float br[95];
  int t = threadIdx.x;
  int qt = blockIdx.x, bn = blockIdx.y;
  int b = bn >> 4, n = bn & 15;
  int i0 = qt << 6;
  int il = t >> 2, lane4 = t & 3;
  int d0 = lane4 << 4;
  const float* qrow = qh + (((size_t)(i0 + il) * BSZV + b) * NH + n) * 64;
  float4 qreg[16];
#pragma unroll
  for (int c = 0; c < 16; ++c) qreg[c] = *(const float4*)(qrow + 4 * c);
  float acc[16] = {};
  float m_i = -INFINITY, l_i = 0.f;
  const float* rwb = rwb_ + n * 64;
  const float* rrb = rrb_ + n * 64;
  int ntiles = 2 * qt + 2;
  for (int jt = 0; jt < ntiles; ++jt) {
    int j0 = jt << 5;
    // stage K, V tiles (32 rows x 64)
    for (int e = t; e < 512; e += 256) {
      int jl = e >> 4, dc = e & 15;
      size_t gidx = (((size_t)(j0 + jl) * BSZV + b) * NH + n) * 16 + dc;
      sK[jl][dc] = ((const float4*)kh)[gidx];
      sV[jl][dc] = ((const float4*)vh)[gidx];
    }
    // stage r band: 95 rows starting at g0 (clamped; clamped rows are masked anyway)
    int g0 = (L - 64) - i0 + j0;
    for (int e = t; e < 95 * 16; e += 256) {
      int s = e >> 4, dc = e & 15;
      int g = g0 + s;
      if (g > L - 1) g = L - 1;
      sR[s][dc] = ((const float4*)rhk)[(size_t)g * 256 + n * 16 + dc];
    }
    __syncthreads();
    // bias dot vectors
    if (t < 32) {
      float s = 0.f;
#pragma unroll
      for (int c = 0; c < 16; ++c) {
        float4 kv = sK[t][c];
        s += rwb[4 * c] * kv.x + rwb[4 * c + 1] * kv.y + rwb[4 * c + 2] * kv.z + rwb[4 * c + 3] * kv.w;
      }
      bk[t] = s;
    } else if (t < 127) {
      int rl = t - 32;
      float s = 0.f;
#pragma unroll
      for (int c = 0; c < 16; ++c) {
        float4 rv = sR[rl][c];
        s += rrb[4 * c] * rv.x + rrb[4 * c + 1] * rv.y + rrb[4 * c + 2] * rv.z + rrb[4 * c + 3] * rv.w;
      }
      br[rl] = s;
    }
    __syncthreads();
    // scores: thread handles row il, cols jl = lane4 + 4u
    float p[8];
    float tmax = -INFINITY;
#pragma unroll
    for (int u = 0; u < 8; ++u) {
      int jl = lane4 + (u << 2);
      int rl = 63 + jl - il;
      float s1 = 0.f, s2 = 0.f;
#pragma unroll
      for (int c = 0; c < 16; ++c) {
        float4 kv = sK[jl][c];
        float4 rv = sR[rl][c];
        float4 qv = qreg[c];
        s1 += qv.x * kv.x + qv.y * kv.y + qv.z * kv.z + qv.w * kv.w;
        s2 += qv.x * rv.x + qv.y * rv.y + qv.z * rv.z + qv.w * rv.w;
      }
      float sc = (s1 + s2 + bk[jl] + br[rl]) * SCALEF;
      if (j0 + jl > i0 + il) sc = NEGF;
      p[u] = sc;
      tmax = fmaxf(tmax, sc);
    }
    tmax = fmaxf(tmax, __shfl_xor(tmax, 1, 4));
    tmax = fmaxf(tmax, __shfl_xor(tmax, 2, 4));
    float m_new = fmaxf(m_i, tmax);
    float alpha = __expf(m_i - m_new);
    float psum = 0.f;
#pragma unroll
    for (int u = 0; u < 8; ++u) {
      p[u] = __expf(p[u] - m_new);
      psum += p[u];
    }
    psum += __shfl_xor(psum, 1, 4);
    psum += __shfl_xor(psum, 2, 4);
    l_i = l_i * alpha + psum;
    m_i = m_new;
#pragma unroll
    for (int c = 0; c < 16; ++c) acc[c] *= alpha;
    // PV: acc[d0..d0+15] += sum_j p_j * V[j][d]
#pragma unroll
    for (int u = 0; u < 8; ++u) {
#pragma unroll
      for (int s4 = 0; s4 < 4; ++s4) {
        float pj = __shfl(p[u], s4, 4);
        int jl = (u << 2) + s4;
#pragma unroll
        for (int c = 0; c < 4; ++c) {
          float4 vv = sV[jl][(lane4 << 2) + c];
          acc[4 * c + 0] = fmaf(pj, vv.x, acc[4 * c + 0]);
          acc[4 * c + 1] = fmaf(pj, vv.y, acc[4 * c + 1]);
          acc[4 * c + 2] = fmaf(pj, vv.z, acc[4 * c + 2]);
          acc[4 * c + 3] = fmaf(pj, vv.w, acc[4 * c + 3]);
        }
      }
    }
    __syncthreads();
  }
  float inv = 1.0f / l_i;
  float* op = vec + ((size_t)(i0 + il) * BSZV + b) * 1024 + n * 64 + d0;
#pragma unroll
  for (int c = 0; c < 4; ++c) {
    float4 o = make_float4(acc[4 * c] * inv, acc[4 * c + 1] * inv, acc[4 * c + 2] * inv, acc[4 * c + 3] * inv);
    *(float4*)(op + 4 * c) = o;
  }
}

// ---------------- residual + layernorm ----------------
__global__ __launch_bounds__(256) void resid_ln(const float* __restrict__ w,
                                                const float* __restrict__ attn,
                                                const float* __restrict__ gamma,
                                                const float* __restrict__ beta,
                                                float* __restrict__ out) {
  __shared__ float ssum[4], ssq[4];
  int row = blockIdx.x, t = threadIdx.x;
  float4 xw = *(const float4*)&w[(size_t)row * 1024 + t * 4];
  float4 xa = *(const float4*)&attn[(size_t)row * 1024 + t * 4];
  float4 x = make_float4(xw.x + xa.x, xw.y + xa.y, xw.z + xa.z, xw.w + xa.w);
  float s = x.x + x.y + x.z + x.w;
  float sq = x.x * x.x + x.y * x.y + x.z * x.z + x.w * x.w;
#pragma unroll
  for (int off = 32; off > 0; off >>= 1) {
    s += __shfl_down(s, off);
    sq += __shfl_down(sq, off);
  }
  int wid = t >> 6;
  if ((t & 63) == 0) { ssum[wid] = s; ssq[wid] = sq; }
  __syncthreads();
  s = ssum[0] + ssum[1] + ssum[2] + ssum[3];
  sq = ssq[0] + ssq[1] + ssq[2] + ssq[3];
  float mean = s * (1.0f / 1024.0f);
  float var = sq * (1.0f / 1024.0f) - mean * mean;
  float rstd = rsqrtf(var + 1e-5f);
  float4 g = *(const float4*)&gamma[t * 4];
  float4 bb = *(const float4*)&beta[t * 4];
  float4 o;
  o.x = (x.x - mean) * rstd * g.x + bb.x;
  o.y = (x.y - mean) * rstd * g.y + bb.y;
  o.z = (x.z - mean) * rstd * g.z + bb.z;
  o.w = (x.w - mean) * rstd * g.w + bb.w;
  *(float4*)&out[(size_t)row * 1024 + t * 4] = o;
}

extern "C" void kernel_launch(void* const* d_in, const int* in_sizes, int n_in,
                              void* d_out, int out_size, void* d_ws, size_t ws_size,
                              hipStream_t stream) {
  const float* w     = (const float*)d_in[0];
  const float* r     = (const float*)d_in[1];
  const float* rwb   = (const float*)d_in[2];
  const float* rrb   = (const float*)d_in[3];
  const float* W_qkv = (const float*)d_in[4];
  const float* W_r   = (const float*)d_in[5];
  const float* W_o   = (const float*)d_in[6];
  const float* cwq   = (const float*)d_in[7];
  const float* cbq   = (const float*)d_in[8];
  const float* cwk   = (const float*)d_in[9];
  const float* cbk   = (const float*)d_in[10];
  const float* cwv   = (const float*)d_in[11];
  const float* cbv   = (const float*)d_in[12];
  const float* gamma = (const float*)d_in[13];
  const float* beta  = (const float*)d_in[14];

  float* ws   = (float*)d_ws;
  float* tmp  = ws;               // 4,194,304 floats (hq/hk/hv staging; later reused for vec)
  float* qh   = ws + 4194304;     // 4,194,304
  float* kh   = ws + 8388608;     // 4,194,304
  float* vh   = ws + 12582912;    // 4,194,304
  float* rhk  = ws + 16777216;    // 1,048,576
  float* vecb = ws;               // reuse tmp
  float* attn = ws + 17825792;    // 4,194,304  (total 22,020,096 floats = 88 MB)
  float* outp = (float*)d_out;

  dim3 blk(256);
  const float* cw[3] = {cwq, cwk, cwv};
  const float* cb[3] = {cbq, cbk, cbv};
  float* dst[3] = {qh, kh, vh};
  for (int sel = 0; sel < 3; ++sel) {
    gemm_nt<<<dim3(16, 64), blk, 0, stream>>>(w, W_qkv + (size_t)sel * 1024 * 1024, tmp, 4096, 1024, 1024);
    conv_head<<<dim3(16, 64), blk, 0, stream>>>(tmp, cw[sel], cb[sel], dst[sel]);
  }
  gemm_nt<<<dim3(16, 16), blk, 0, stream>>>(r, W_r, rhk, 1024, 1024, 1024);
  rel_attn<<<dim3(16, 64), blk, 0, stream>>>(qh, kh, vh, rhk, rwb, rrb, vecb);
  gemm_nt<<<dim3(16, 64), blk, 0, stream>>>(vecb, W_o, attn, 4096, 1024, 1024);
  resid_ln<<<4096, blk, 0, stream>>>(w, attn, gamma, beta, outp);
}

// Round 2
// 344.148 us; speedup vs baseline: 5.8071x; 5.8071x over previous
//
#include <hip/hip_runtime.h>
#include <math.h>

#define L 1024
#define SCALEF 0.125f
#define NEGF -1e30f

typedef unsigned short u16;
typedef __bf16 bf16x8 __attribute__((ext_vector_type(8)));
typedef float f32x4 __attribute__((ext_vector_type(4)));
typedef unsigned short u16x8 __attribute__((ext_vector_type(8)));
typedef unsigned short u16x4 __attribute__((ext_vector_type(4)));

#define MFMA(a, b, c) __builtin_amdgcn_mfma_f32_16x16x32_bf16(a, b, c, 0, 0, 0)

__device__ inline u16 f2b(float f) {
  union { float f; unsigned u; } v; v.f = f;
  unsigned r = v.u + 0x7fffu + ((v.u >> 16) & 1u);
  return (u16)(r >> 16);
}

// ---------------- cast fp32 -> bf16 (vectorized by 4) ----------------
__global__ __launch_bounds__(256) void cast_bf16(const float* __restrict__ src,
                                                 u16* __restrict__ dst, int nvec) {
  int i = blockIdx.x * 256 + threadIdx.x;
  if (i < nvec) {
    float4 v = ((const float4*)src)[i];
    u16x4 o = {f2b(v.x), f2b(v.y), f2b(v.z), f2b(v.w)};
    ((u16x4*)dst)[i] = o;
  }
}

// conv weight [64][64][7] fp32 -> [7][64][64] bf16
__global__ __launch_bounds__(256) void convw_t(const float* __restrict__ src, u16* __restrict__ dst) {
  int i = blockIdx.x * 256 + threadIdx.x;
  if (i < 7 * 64 * 64) {
    int tt = i >> 12, rem = i & 4095;
    int dout = rem >> 6, din = rem & 63;
    dst[i] = f2b(src[(dout * 64 + din) * 7 + tt]);
  }
}

// ---------------- MFMA GEMM: C[M,N] = A[M,K] * B[N,K]^T, A/B bf16, C bf16 or f32 ----------------
template <int OB>
__global__ __launch_bounds__(256) void mfma_gemm_nt(const u16* __restrict__ A, const u16* __restrict__ B,
                                                    void* __restrict__ Cp, int M, int N, int K) {
  __shared__ u16 sA[128 * 32];
  __shared__ u16 sB[128 * 32];
  int t = threadIdx.x;
  int w = t >> 6, lane = t & 63;
  int q4 = lane >> 4, li = lane & 15;
  int m0 = blockIdx.y << 7, n0 = blockIdx.x << 7;
  int mw = (w & 1) << 6, nw = (w >> 1) << 6;
  f32x4 acc[4][4];
  for (int i = 0; i < 4; ++i)
    for (int j = 0; j < 4; ++j) acc[i][j] = (f32x4){0.f, 0.f, 0.f, 0.f};
  int r0 = t >> 2, c0 = (t & 3) << 3;
  const u16* Ap0 = A + (size_t)(m0 + r0) * K + c0;
  const u16* Ap1 = A + (size_t)(m0 + 64 + r0) * K + c0;
  const u16* Bp0 = B + (size_t)(n0 + r0) * K + c0;
  const u16* Bp1 = B + (size_t)(n0 + 64 + r0) * K + c0;
  for (int kb = 0; kb < K; kb += 32) {
    u16x8 a0 = *(const u16x8*)(Ap0 + kb);
    u16x8 a1 = *(const u16x8*)(Ap1 + kb);
    u16x8 b0 = *(const u16x8*)(Bp0 + kb);
    u16x8 b1 = *(const u16x8*)(Bp1 + kb);
    __syncthreads();
    *(u16x8*)&sA[r0 * 32 + c0] = a0;
    *(u16x8*)&sA[(64 + r0) * 32 + c0] = a1;
    *(u16x8*)&sB[r0 * 32 + c0] = b0;
    *(u16x8*)&sB[(64 + r0) * 32 + c0] = b1;
    __syncthreads();
    bf16x8 fa[4], fb[4];
#pragma unroll
    for (int i = 0; i < 4; ++i) fa[i] = *(const bf16x8*)&sA[(mw + i * 16 + li) * 32 + q4 * 8];
#pragma unroll
    for (int i = 0; i < 4; ++i) fb[i] = *(const bf16x8*)&sB[(nw + i * 16 + li) * 32 + q4 * 8];
#pragma unroll
    for (int mt = 0; mt < 4; ++mt)
#pragma unroll
      for (int nt = 0; nt < 4; ++nt) acc[mt][nt] = MFMA(fa[mt], fb[nt], acc[mt][nt]);
  }
#pragma unroll
  for (int mt = 0; mt < 4; ++mt)
#pragma unroll
    for (int r = 0; r < 4; ++r) {
      size_t row = m0 + mw + mt * 16 + q4 * 4 + r;
      if (OB) {
        u16* C = (u16*)Cp;
#pragma unroll
        for (int nt = 0; nt < 4; ++nt) C[row * N + n0 + nw + nt * 16 + li] = f2b(acc[mt][nt][r]);
      } else {
        float* C = (float*)Cp;
#pragma unroll
        for (int nt = 0; nt < 4; ++nt) C[row * N + n0 + nw + nt * 16 + li] = acc[mt][nt][r];
      }
    }
}

// ---------------- conv1d k=7 via 7 accumulated MFMA GEMMs ----------------
// x: heads bf16 [l*4+b][3072], use cols [selOff + n*64, +64). out: bf16 [L][B][NH][64]
__global__ __launch_bounds__(256) void conv_mfma(const u16* __restrict__ x, const u16* __restrict__ wT,
                                                 const float* __restrict__ bias, u16* __restrict__ out,
                                                 int selOff) {
  __shared__ u16 sX[70][72];
  int t = threadIdx.x;
  int w = t >> 6, lane = t & 63;
  int q4 = lane >> 4, li = lane & 15;
  int l0 = blockIdx.x << 6, bn = blockIdx.y;
  int b = bn >> 4, n = bn & 15;
  const u16* xb = x + b * 3072 + selOff + n * 64;
  for (int e = t; e < 70 * 8; e += 256) {
    int ro = e >> 3, c = e & 7;
    int l = l0 - 3 + ro;
    u16x8 v = {0, 0, 0, 0, 0, 0, 0, 0};
    if (l >= 0 && l < L) v = *(const u16x8*)(xb + (size_t)l * 12288 + c * 8);
    *(u16x8*)&sX[ro][c * 8] = v;
  }
  bf16x8 Bw[7][2];
#pragma unroll
  for (int tt = 0; tt < 7; ++tt)
#pragma unroll
    for (int kc = 0; kc < 2; ++kc)
      Bw[tt][kc] = *(const bf16x8*)(wT + (tt * 64 + w * 16 + li) * 64 + kc * 32 + q4 * 8);
  f32x4 acc[4];
#pragma unroll
  for (int i = 0; i < 4; ++i) acc[i] = (f32x4){0.f, 0.f, 0.f, 0.f};
  __syncthreads();
#pragma unroll
  for (int tt = 0; tt < 7; ++tt)
#pragma unroll
    for (int kc = 0; kc < 2; ++kc)
#pragma unroll
      for (int mt = 0; mt < 4; ++mt) {
        bf16x8 a = *(const bf16x8*)&sX[mt * 16 + li + tt][kc * 32 + q4 * 8];
        acc[mt] = MFMA(a, Bw[tt][kc], acc[mt]);
      }
  float bv = bias[w * 16 + li];
#pragma unroll
  for (int mt = 0; mt < 4; ++mt)
#pragma unroll
    for (int r = 0; r < 4; ++r) {
      int l = l0 + mt * 16 + q4 * 4 + r;
      out[(((size_t)l * 4 + b) * 16 + n) * 64 + w * 16 + li] = f2b(acc[mt][r] + bv);
    }
}

// ---------------- MFMA flash attention with relative shift ----------------
// qh/kh/vh: bf16 [L][4][16][64]; rhk: bf16 [1024][1024]; vec: bf16 [L][4][1024]
__global__ __launch_bounds__(256) void rel_attn(const u16* __restrict__ qh, const u16* __restrict__ kh,
                                                const u16* __restrict__ vh, const u16* __restrict__ rhk,
                                                const float* __restrict__ rwb_, const float* __restrict__ rrb_,
                                                u16* __restrict__ vec) {
  __shared__ u16 sK[64][72];
  __shared__ u16 sVt[64][72];
  __shared__ u16 sR[128][72];
  __shared__ float sG[4][16][83];
  __shared__ u16 sP[4][16][72];
  int t = threadIdx.x;
  int w = t >> 6, lane = t & 63;
  int q4 = lane >> 4, li = lane & 15;
  int p = blockIdx.x, bn = blockIdx.y;
  int b = bn >> 4, n = bn & 15;
  float rwbv[2][8], rrbv[2][8];
#pragma unroll
  for (int kc = 0; kc < 2; ++kc)
#pragma unroll
    for (int j = 0; j < 8; ++j) {
      int d = kc * 32 + q4 * 8 + j;
      rwbv[kc][j] = rwb_[n * 64 + d];
      rrbv[kc][j] = rrb_[n * 64 + d];
    }
  int base_w = 48 - w * 16;
  for (int half = 0; half < 2; ++half) {
    int qt = (half == 0) ? p : 15 - p;
    int i0 = qt << 6;
    bf16x8 Aw[2], Ar[2];
    {
      const u16* qrow = qh + (((size_t)(i0 + w * 16 + li) * 4 + b) * 16 + n) * 64;
#pragma unroll
      for (int kc = 0; kc < 2; ++kc) {
        bf16x8 qv = *(const bf16x8*)(qrow + kc * 32 + q4 * 8);
        bf16x8 aw, ar;
#pragma unroll
        for (int j = 0; j < 8; ++j) {
          float qf = (float)qv[j];
          aw[j] = (__bf16)(qf + rwbv[kc][j]);
          ar[j] = (__bf16)(qf + rrbv[kc][j]);
        }
        Aw[kc] = aw;
        Ar[kc] = ar;
      }
    }
    f32x4 accO[4];
#pragma unroll
    for (int i = 0; i < 4; ++i) accO[i] = (f32x4){0.f, 0.f, 0.f, 0.f};
    float mst[4], lst[4];
#pragma unroll
    for (int r = 0; r < 4; ++r) { mst[r] = -INFINITY; lst[r] = 0.f; }
    int ntile = qt + 1;
    for (int jt = 0; jt < ntile; ++jt) {
      int j0 = jt << 6;
      int gB = 960 - i0 + j0;
      // stage K (64x64)
      for (int e = t; e < 512; e += 256) {
        int row = e >> 3, c = e & 7;
        *(u16x8*)&sK[row][c * 8] =
            *(const u16x8*)(kh + (((size_t)(j0 + row) * 4 + b) * 16 + n) * 64 + c * 8);
      }
      // stage V transposed (sVt[d][j])
      for (int e = t; e < 512; e += 256) {
        int jl = e >> 3, c = e & 7;
        u16x8 v = *(const u16x8*)(vh + (((size_t)(j0 + jl) * 4 + b) * 16 + n) * 64 + c * 8);
#pragma unroll
        for (int j = 0; j < 8; ++j) sVt[c * 8 + j][jl] = v[j];
      }
      // stage R band (128 rows, clamped rows feed only masked entries)
      for (int e = t; e < 1024; e += 256) {
        int m = e >> 3, c = e & 7;
        int g = gB + m;
        if (g > L - 1) g = L - 1;
        *(u16x8*)&sR[m][c * 8] = *(const u16x8*)(rhk + (size_t)g * 1024 + n * 64 + c * 8);
      }
      __syncthreads();
      f32x4 accS[4], accG[5];
#pragma unroll
      for (int i = 0; i < 4; ++i) accS[i] = (f32x4){0.f, 0.f, 0.f, 0.f};
#pragma unroll
      for (int i = 0; i < 5; ++i) accG[i] = (f32x4){0.f, 0.f, 0.f, 0.f};
#pragma unroll
      for (int kc = 0; kc < 2; ++kc) {
#pragma unroll
        for (int nt = 0; nt < 4; ++nt) {
          bf16x8 fk = *(const bf16x8*)&sK[nt * 16 + li][kc * 32 + q4 * 8];
          accS[nt] = MFMA(Aw[kc], fk, accS[nt]);
        }
#pragma unroll
        for (int nt = 0; nt < 5; ++nt) {
          bf16x8 fr = *(const bf16x8*)&sR[base_w + nt * 16 + li][kc * 32 + q4 * 8];
          accG[nt] = MFMA(Ar[kc], fr, accG[nt]);
        }
      }
#pragma unroll
      for (int nt = 0; nt < 5; ++nt)
#pragma unroll
        for (int r = 0; r < 4; ++r) sG[w][q4 * 4 + r][nt * 16 + li] = accG[nt][r];
      __syncthreads();
      float Sv[4][4];
#pragma unroll
      for (int nt = 0; nt < 4; ++nt) {
        int jl = nt * 16 + li;
#pragma unroll
        for (int r = 0; r < 4; ++r) {
          int il = q4 * 4 + r;
          float g = sG[w][il][15 - il + jl];
          float s = (accS[nt][r] + g) * SCALEF;
          if (j0 + jl > i0 + w * 16 + il) s = NEGF;
          Sv[nt][r] = s;
        }
      }
      float mnew[4], alpha[4], psum[4];
#pragma unroll
      for (int r = 0; r < 4; ++r) {
        float mx = fmaxf(fmaxf(Sv[0][r], Sv[1][r]), fmaxf(Sv[2][r], Sv[3][r]));
        mx = fmaxf(mx, __shfl_xor(mx, 1));
        mx = fmaxf(mx, __shfl_xor(mx, 2));
        mx = fmaxf(mx, __shfl_xor(mx, 4));
        mx = fmaxf(mx, __shfl_xor(mx, 8));
        mnew[r] = fmaxf(mst[r], mx);
        alpha[r] = __expf(mst[r] - mnew[r]);
        psum[r] = 0.f;
      }
#pragma unroll
      for (int nt = 0; nt < 4; ++nt)
#pragma unroll
        for (int r = 0; r < 4; ++r) {
          float pv = __expf(Sv[nt][r] - mnew[r]);
          psum[r] += pv;
          sP[w][q4 * 4 + r][nt * 16 + li] = f2b(pv);
        }
#pragma unroll
      for (int r = 0; r < 4; ++r) {
        float ps = psum[r];
        ps += __shfl_xor(ps, 1);
        ps += __shfl_xor(ps, 2);
        ps += __shfl_xor(ps, 4);
        ps += __shfl_xor(ps, 8);
        lst[r] = lst[r] * alpha[r] + ps;
        mst[r] = mnew[r];
      }
#pragma unroll
      for (int nt = 0; nt < 4; ++nt) {
        f32x4 o = accO[nt];
#pragma unroll
        for (int r = 0; r < 4; ++r) o[r] *= alpha[r];
        accO[nt] = o;
      }
      __syncthreads();
#pragma unroll
      for (int kc = 0; kc < 2; ++kc) {
        bf16x8 ap = *(const bf16x8*)&sP[w][li][kc * 32 + q4 * 8];
#pragma unroll
        for (int nt = 0; nt < 4; ++nt) {
          bf16x8 fv = *(const bf16x8*)&sVt[nt * 16 + li][kc * 32 + q4 * 8];
          accO[nt] = MFMA(ap, fv, accO[nt]);
        }
      }
      __syncthreads();
    }
#pragma unroll
    for (int r = 0; r < 4; ++r) {
      int il = q4 * 4 + r;
      int ig = i0 + w * 16 + il;
      float inv = 1.0f / lst[r];
      u16* orow = vec + (((size_t)ig * 4 + b) * 16 + n) * 64;
#pragma unroll
      for (int nt = 0; nt < 4; ++nt) orow[nt * 16 + li] = f2b(accO[nt][r] * inv);
    }
    __syncthreads();
  }
}

// ---------------- residual + layernorm ----------------
__global__ __launch_bounds__(256) void resid_ln(const float* __restrict__ w,
                                                const float* __restrict__ attn,
                                                const float* __restrict__ gamma,
                                                const float* __restrict__ beta,
                                                float* __restrict__ out) {
  __shared__ float ssum[4], ssq[4];
  int row = blockIdx.x, t = threadIdx.x;
  float4 xw = *(const float4*)&w[(size_t)row * 1024 + t * 4];
  float4 xa = *(const float4*)&attn[(size_t)row * 1024 + t * 4];
  float4 x = make_float4(xw.x + xa.x, xw.y + xa.y, xw.z + xa.z, xw.w + xa.w);
  float s = x.x + x.y + x.z + x.w;
  float sq = x.x * x.x + x.y * x.y + x.z * x.z + x.w * x.w;
#pragma unroll
  for (int off = 32; off > 0; off >>= 1) {
    s += __shfl_down(s, off);
    sq += __shfl_down(sq, off);
  }
  int wid = t >> 6;
  if ((t & 63) == 0) { ssum[wid] = s; ssq[wid] = sq; }
  __syncthreads();
  s = ssum[0] + ssum[1] + ssum[2] + ssum[3];
  sq = ssq[0] + ssq[1] + ssq[2] + ssq[3];
  float mean = s * (1.0f / 1024.0f);
  float var = sq * (1.0f / 1024.0f) - mean * mean;
  float rstd = rsqrtf(var + 1e-5f);
  float4 g = *(const float4*)&gamma[t * 4];
  float4 bb = *(const float4*)&beta[t * 4];
  float4 o;
  o.x = (x.x - mean) * rstd * g.x + bb.x;
  o.y = (x.y - mean) * rstd * g.y + bb.y;
  o.z = (x.z - mean) * rstd * g.z + bb.z;
  o.w = (x.w - mean) * rstd * g.w + bb.w;
  *(float4*)&out[(size_t)row * 1024 + t * 4] = o;
}

extern "C" void kernel_launch(void* const* d_in, const int* in_sizes, int n_in,
                              void* d_out, int out_size, void* d_ws, size_t ws_size,
                              hipStream_t stream) {
  const float* w     = (const float*)d_in[0];
  const float* r     = (const float*)d_in[1];
  const float* rwb   = (const float*)d_in[2];
  const float* rrb   = (const float*)d_in[3];
  const float* W_qkv = (const float*)d_in[4];
  const float* W_r   = (const float*)d_in[5];
  const float* W_o   = (const float*)d_in[6];
  const float* cwq   = (const float*)d_in[7];
  const float* cbq   = (const float*)d_in[8];
  const float* cwk   = (const float*)d_in[9];
  const float* cbk   = (const float*)d_in[10];
  const float* cwv   = (const float*)d_in[11];
  const float* cbv   = (const float*)d_in[12];
  const float* gamma = (const float*)d_in[13];
  const float* beta  = (const float*)d_in[14];
  float* outp = (float*)d_out;

  char* wsb = (char*)d_ws;
  u16*   heads   = (u16*)(wsb);                 // 25,165,824 B [4096][3072] bf16
  u16*   vec     = (u16*)(wsb);                 // alias: heads dead after convs
  float* attnf   = (float*)(wsb + 8388608);     // 16 MB, within heads region
  u16*   qh      = (u16*)(wsb + 25165824);
  u16*   kh      = (u16*)(wsb + 33554432);
  u16*   vh      = (u16*)(wsb + 41943040);
  u16*   rhk     = (u16*)(wsb + 50331648);
  u16*   w_bf    = (u16*)(wsb + 52428800);
  u16*   wqkv_bf = (u16*)(wsb + 60817408);
  u16*   r_bf    = (u16*)(wsb + 67108864);
  u16*   wr_bf   = (u16*)(wsb + 69206016);
  u16*   wo_bf   = (u16*)(wsb + 71303168);
  u16*   wTq     = (u16*)(wsb + 73400320);
  u16*   wTk     = (u16*)(wsb + 73457664);
  u16*   wTv     = (u16*)(wsb + 73515008);

  dim3 blk(256);
  cast_bf16<<<4096, blk, 0, stream>>>(w, w_bf, 1048576);
  cast_bf16<<<3072, blk, 0, stream>>>(W_qkv, wqkv_bf, 786432);
  cast_bf16<<<1024, blk, 0, stream>>>(r, r_bf, 262144);
  cast_bf16<<<1024, blk, 0, stream>>>(W_r, wr_bf, 262144);
  cast_bf16<<<1024, blk, 0, stream>>>(W_o, wo_bf, 262144);
  convw_t<<<112, blk, 0, stream>>>(cwq, wTq);
  convw_t<<<112, blk, 0, stream>>>(cwk, wTk);
  convw_t<<<112, blk, 0, stream>>>(cwv, wTv);

  mfma_gemm_nt<1><<<dim3(24, 32), blk, 0, stream>>>(w_bf, wqkv_bf, heads, 4096, 3072, 1024);
  conv_mfma<<<dim3(16, 64), blk, 0, stream>>>(heads, wTq, cbq, qh, 0);
  conv_mfma<<<dim3(16, 64), blk, 0, stream>>>(heads, wTk, cbk, kh, 1024);
  conv_mfma<<<dim3(16, 64), blk, 0, stream>>>(heads, wTv, cbv, vh, 2048);
  mfma_gemm_nt<1><<<dim3(8, 8), blk, 0, stream>>>(r_bf, wr_bf, rhk, 1024, 1024, 1024);
  rel_attn<<<dim3(8, 64), blk, 0, stream>>>(qh, kh, vh, rhk, rwb, rrb, vec);
  mfma_gemm_nt<0><<<dim3(8, 32), blk, 0, stream>>>(vec, wo_bf, attnf, 4096, 1024, 1024);
  resid_ln<<<4096, blk, 0, stream>>>(w, attnf, gamma, beta, outp);
}

// Round 3
// 311.286 us; speedup vs baseline: 6.4202x; 1.1056x over previous
//
#include <hip/hip_runtime.h>
#include <math.h>

#define L 1024
#define SCALEF 0.125f
#define NEGF -1e30f

typedef unsigned short u16;
typedef __bf16 bf16x8 __attribute__((ext_vector_type(8)));
typedef float f32x4 __attribute__((ext_vector_type(4)));
typedef unsigned short u16x8 __attribute__((ext_vector_type(8)));
typedef unsigned short u16x4 __attribute__((ext_vector_type(4)));

#define MFMA(a, b, c) __builtin_amdgcn_mfma_f32_16x16x32_bf16(a, b, c, 0, 0, 0)

__device__ inline u16 f2b(float f) {
  union { float f; unsigned u; } v; v.f = f;
  unsigned r = v.u + 0x7fffu + ((v.u >> 16) & 1u);
  return (u16)(r >> 16);
}

// async global->LDS, 16B per lane; lds must be wave-uniform base (HW scatters lane*16)
__device__ __forceinline__ void ld16(u16* lds, const u16* g) {
  __builtin_amdgcn_global_load_lds((const __attribute__((address_space(1))) unsigned int*)g,
                                   (__attribute__((address_space(3))) unsigned int*)lds, 16, 0, 0);
}

// ---------------- prep: all fp32->bf16 casts + conv weight transposes, one launch ----------------
__global__ __launch_bounds__(256) void prep(const float* __restrict__ w, const float* __restrict__ Wqkv,
                                            const float* __restrict__ r, const float* __restrict__ Wr,
                                            const float* __restrict__ Wo,
                                            const float* __restrict__ cwq, const float* __restrict__ cwk,
                                            const float* __restrict__ cwv,
                                            u16* w_bf, u16* wqkv_bf, u16* r_bf, u16* wr_bf, u16* wo_bf,
                                            u16* wTq, u16* wTk, u16* wTv) {
  int i = blockIdx.x * 256 + threadIdx.x;
  if (i < 2621440) {
    const float* s; u16* d; int off;
    if (i < 1048576)      { s = w;    d = w_bf;    off = i; }
    else if (i < 1835008) { s = Wqkv; d = wqkv_bf; off = i - 1048576; }
    else if (i < 2097152) { s = r;    d = r_bf;    off = i - 1835008; }
    else if (i < 2359296) { s = Wr;   d = wr_bf;   off = i - 2097152; }
    else                  { s = Wo;   d = wo_bf;   off = i - 2359296; }
    float4 v = ((const float4*)s)[off];
    u16x4 o = {f2b(v.x), f2b(v.y), f2b(v.z), f2b(v.w)};
    ((u16x4*)d)[off] = o;
  } else {
    int j = i - 2621440;
    if (j < 86016) {
      int z = j / 28672, rem = j % 28672;
      const float* src = z == 0 ? cwq : z == 1 ? cwk : cwv;
      u16* dst = z == 0 ? wTq : z == 1 ? wTk : wTv;
      int tt = rem >> 12, rem2 = rem & 4095;
      int dout = rem2 >> 6, din = rem2 & 63;
      dst[rem] = f2b(src[(dout * 64 + din) * 7 + tt]);
    }
  }
}

// ---------------- 128x128 MFMA GEMM tile, async staging: C = A[M,K] * B[N,K]^T ----------------
template <int OB>
__device__ __forceinline__ void gemm_tile(u16* sA, u16* sB, const u16* A, const u16* B,
                                          void* Cp, int N, int K, int m0, int n0) {
  int t = threadIdx.x;
  int w = t >> 6, lane = t & 63;
  int q4 = lane >> 4, li = lane & 15;
  int mw = (w & 1) << 6, nw = (w >> 1) << 6;
  f32x4 acc[4][4];
#pragma unroll
  for (int i = 0; i < 4; ++i)
#pragma unroll
    for (int j = 0; j < 4; ++j) acc[i][j] = (f32x4){0.f, 0.f, 0.f, 0.f};
  int r0 = t >> 2, c0 = (t & 3) << 3;
  const u16* Ap0 = A + (size_t)(m0 + r0) * K + c0;
  const u16* Ap1 = A + (size_t)(m0 + 64 + r0) * K + c0;
  const u16* Bp0 = B + (size_t)(n0 + r0) * K + c0;
  const u16* Bp1 = B + (size_t)(n0 + 64 + r0) * K + c0;
  u16* sAw = sA + w * 512;   // byte base w*1024
  u16* sBw = sB + w * 512;
  for (int kb = 0; kb < K; kb += 32) {
    __syncthreads();
    ld16(sAw, Ap0 + kb);
    ld16(sAw + 2048, Ap1 + kb);
    ld16(sBw, Bp0 + kb);
    ld16(sBw + 2048, Bp1 + kb);
    __syncthreads();
    bf16x8 fa[4], fb[4];
#pragma unroll
    for (int i = 0; i < 4; ++i) fa[i] = *(const bf16x8*)&sA[(mw + i * 16 + li) * 32 + q4 * 8];
#pragma unroll
    for (int i = 0; i < 4; ++i) fb[i] = *(const bf16x8*)&sB[(nw + i * 16 + li) * 32 + q4 * 8];
#pragma unroll
    for (int mt = 0; mt < 4; ++mt)
#pragma unroll
      for (int nt = 0; nt < 4; ++nt) acc[mt][nt] = MFMA(fa[mt], fb[nt], acc[mt][nt]);
  }
#pragma unroll
  for (int mt = 0; mt < 4; ++mt)
#pragma unroll
    for (int r = 0; r < 4; ++r) {
      size_t row = m0 + mw + mt * 16 + q4 * 4 + r;
      if (OB) {
        u16* C = (u16*)Cp;
#pragma unroll
        for (int nt = 0; nt < 4; ++nt) C[row * N + n0 + nw + nt * 16 + li] = f2b(acc[mt][nt][r]);
      } else {
        float* C = (float*)Cp;
#pragma unroll
        for (int nt = 0; nt < 4; ++nt) C[row * N + n0 + nw + nt * 16 + li] = acc[mt][nt][r];
      }
    }
}

// fused QKV (768 blocks) + r (64 blocks) GEMM, both K=1024, bf16 out
__global__ __launch_bounds__(256) void gemm_stage1(const u16* __restrict__ w_bf, const u16* __restrict__ wqkv_bf,
                                                   u16* __restrict__ heads,
                                                   const u16* __restrict__ r_bf, const u16* __restrict__ wr_bf,
                                                   u16* __restrict__ rhk) {
  __shared__ u16 sA[128 * 32];
  __shared__ u16 sB[128 * 32];
  int id = blockIdx.x;
  if (id < 768) {
    gemm_tile<1>(sA, sB, w_bf, wqkv_bf, heads, 3072, 1024, (id / 24) << 7, (id % 24) << 7);
  } else {
    int j = id - 768;
    gemm_tile<1>(sA, sB, r_bf, wr_bf, rhk, 1024, 1024, (j >> 3) << 7, (j & 7) << 7);
  }
}

// W_o GEMM, fp32 out
__global__ __launch_bounds__(256) void gemm_wo(const u16* __restrict__ vec, const u16* __restrict__ wo_bf,
                                               float* __restrict__ attnf) {
  __shared__ u16 sA[128 * 32];
  __shared__ u16 sB[128 * 32];
  gemm_tile<0>(sA, sB, vec, wo_bf, attnf, 1024, 1024, (int)(blockIdx.y << 7), (int)(blockIdx.x << 7));
}

// ---------------- conv1d k=7 via MFMA; z=0:q, 1:k, 2:v (v written transposed [bn][d][L]) ----------------
__global__ __launch_bounds__(256) void conv3(const u16* __restrict__ x,
                                             const u16* __restrict__ wTq, const u16* __restrict__ wTk,
                                             const u16* __restrict__ wTv,
                                             const float* __restrict__ cbq, const float* __restrict__ cbk,
                                             const float* __restrict__ cbv,
                                             u16* __restrict__ qh, u16* __restrict__ kh, u16* __restrict__ vtg) {
  __shared__ u16 sX[70 * 72];
  int z = blockIdx.z;
  const u16* wT = z == 0 ? wTq : z == 1 ? wTk : wTv;
  const float* bias = z == 0 ? cbq : z == 1 ? cbk : cbv;
  int t = threadIdx.x;
  int w = t >> 6, lane = t & 63;
  int q4 = lane >> 4, li = lane & 15;
  int l0 = blockIdx.x << 6, bn = blockIdx.y;
  int b = bn >> 4, n = bn & 15;
  const u16* xb = x + b * 3072 + z * 1024 + n * 64;
  for (int e = t; e < 560; e += 256) {
    int ro = e >> 3, c = e & 7;
    int l = l0 - 3 + ro;
    u16x8 v = {0, 0, 0, 0, 0, 0, 0, 0};
    if (l >= 0 && l < L) v = *(const u16x8*)(xb + (size_t)l * 12288 + c * 8);
    *(u16x8*)&sX[ro * 72 + c * 8] = v;
  }
  bf16x8 Bw[7][2];
#pragma unroll
  for (int tt = 0; tt < 7; ++tt)
#pragma unroll
    for (int kc = 0; kc < 2; ++kc)
      Bw[tt][kc] = *(const bf16x8*)(wT + (tt * 64 + w * 16 + li) * 64 + kc * 32 + q4 * 8);
  f32x4 acc[4];
#pragma unroll
  for (int i = 0; i < 4; ++i) acc[i] = (f32x4){0.f, 0.f, 0.f, 0.f};
  __syncthreads();
#pragma unroll
  for (int tt = 0; tt < 7; ++tt)
#pragma unroll
    for (int kc = 0; kc < 2; ++kc)
#pragma unroll
      for (int mt = 0; mt < 4; ++mt) {
        bf16x8 a = *(const bf16x8*)&sX[(mt * 16 + li + tt) * 72 + kc * 32 + q4 * 8];
        acc[mt] = MFMA(a, Bw[tt][kc], acc[mt]);
      }
  float bv = bias[w * 16 + li];
  if (z < 2) {
    u16* out = z == 0 ? qh : kh;
#pragma unroll
    for (int mt = 0; mt < 4; ++mt)
#pragma unroll
      for (int r = 0; r < 4; ++r) {
        int l = l0 + mt * 16 + q4 * 4 + r;
        out[(((size_t)l * 4 + b) * 16 + n) * 64 + w * 16 + li] = f2b(acc[mt][r] + bv);
      }
  } else {
    // transpose through LDS (reuse sX): sT[d][l_local], store pattern is 2-way (free)
    __syncthreads();
#pragma unroll
    for (int mt = 0; mt < 4; ++mt)
#pragma unroll
      for (int r = 0; r < 4; ++r)
        sX[(w * 16 + li) * 72 + mt * 16 + q4 * 4 + r] = f2b(acc[mt][r] + bv);
    __syncthreads();
    int d = t >> 2, ch = t & 3;
    u16x8 v0 = *(u16x8*)&sX[d * 72 + ch * 16];
    u16x8 v1 = *(u16x8*)&sX[d * 72 + ch * 16 + 8];
    u16* dst = vtg + ((size_t)bn * 64 + d) * 1024 + l0 + ch * 16;
    *(u16x8*)dst = v0;
    *(u16x8*)(dst + 8) = v1;
  }
}

// ---------------- MFMA flash attention with relative shift ----------------
// qh/kh: bf16 [L][4][16][64]; vt: bf16 [64bn][64d][1024L]; rhk: bf16 [1024][1024]; vec: bf16 [L][4][1024]
__global__ __launch_bounds__(256) void rel_attn(const u16* __restrict__ qh, const u16* __restrict__ kh,
                                                const u16* __restrict__ vt, const u16* __restrict__ rhk,
                                                const float* __restrict__ rwb_, const float* __restrict__ rrb_,
                                                u16* __restrict__ vec) {
  __shared__ u16 sK[64][72];
  __shared__ u16 sVt[64][72];
  __shared__ u16 sR[128][72];
  __shared__ u16 sP[4][16][72];
  int t = threadIdx.x;
  int w = t >> 6, lane = t & 63;
  int q4 = lane >> 4, li = lane & 15;
  int p = blockIdx.x, bn = blockIdx.y;
  int b = bn >> 4, n = bn & 15;
  float rwbv[2][8], rrbv[2][8];
#pragma unroll
  for (int kc = 0; kc < 2; ++kc)
#pragma unroll
    for (int j = 0; j < 8; ++j) {
      int d = kc * 32 + q4 * 8 + j;
      rwbv[kc][j] = rwb_[n * 64 + d];
      rrbv[kc][j] = rrb_[n * 64 + d];
    }
  int base_w = 48 - w * 16;
  const u16* vtb = vt + (size_t)bn * 64 * 1024;
  for (int half = 0; half < 2; ++half) {
    int qt = (half == 0) ? p : 15 - p;
    int i0 = qt << 6;
    bf16x8 Aw[2], Ar[2];
    {
      const u16* qrow = qh + (((size_t)(i0 + w * 16 + li) * 4 + b) * 16 + n) * 64;
#pragma unroll
      for (int kc = 0; kc < 2; ++kc) {
        bf16x8 qv = *(const bf16x8*)(qrow + kc * 32 + q4 * 8);
        bf16x8 aw, ar;
#pragma unroll
        for (int j = 0; j < 8; ++j) {
          float qf = (float)qv[j];
          aw[j] = (__bf16)(qf + rwbv[kc][j]);
          ar[j] = (__bf16)(qf + rrbv[kc][j]);
        }
        Aw[kc] = aw;
        Ar[kc] = ar;
      }
    }
    f32x4 accO[4];
#pragma unroll
    for (int i = 0; i < 4; ++i) accO[i] = (f32x4){0.f, 0.f, 0.f, 0.f};
    float mst[4], lst[4];
#pragma unroll
    for (int r = 0; r < 4; ++r) { mst[r] = -INFINITY; lst[r] = 0.f; }
    int ntile = qt + 1;
    for (int jt = 0; jt < ntile; ++jt) {
      int j0 = jt << 6;
      int gB = 960 - i0 + j0;
      for (int e = t; e < 512; e += 256) {
        int row = e >> 3, c = e & 7;
        *(u16x8*)&sK[row][c * 8] =
            *(const u16x8*)(kh + (((size_t)(j0 + row) * 4 + b) * 16 + n) * 64 + c * 8);
      }
      for (int e = t; e < 512; e += 256) {
        int d = e >> 3, c = e & 7;
        *(u16x8*)&sVt[d][c * 8] = *(const u16x8*)(vtb + (size_t)d * 1024 + j0 + c * 8);
      }
      for (int e = t; e < 1024; e += 256) {
        int m = e >> 3, c = e & 7;
        int g = gB + m;
        if (g > L - 1) g = L - 1;
        *(u16x8*)&sR[m][c * 8] = *(const u16x8*)(rhk + (size_t)g * 1024 + n * 64 + c * 8);
      }
      __syncthreads();
      f32x4 accS[4], accG[5];
#pragma unroll
      for (int i = 0; i < 4; ++i) accS[i] = (f32x4){0.f, 0.f, 0.f, 0.f};
#pragma unroll
      for (int i = 0; i < 5; ++i) accG[i] = (f32x4){0.f, 0.f, 0.f, 0.f};
#pragma unroll
      for (int kc = 0; kc < 2; ++kc) {
#pragma unroll
        for (int nt = 0; nt < 4; ++nt) {
          bf16x8 fk = *(const bf16x8*)&sK[nt * 16 + li][kc * 32 + q4 * 8];
          accS[nt] = MFMA(Aw[kc], fk, accS[nt]);
        }
#pragma unroll
        for (int nt = 0; nt < 5; ++nt) {
          bf16x8 fr = *(const bf16x8*)&sR[base_w + nt * 16 + li][kc * 32 + q4 * 8];
          accG[nt] = MFMA(Ar[kc], fr, accG[nt]);
        }
      }
      // rel-shift via intra-row-group shuffles: need G[il][15-il+jl], row group = 16 lanes
      float Sv[4][4];
#pragma unroll
      for (int nt = 0; nt < 4; ++nt)
#pragma unroll
        for (int r = 0; r < 4; ++r) {
          int il = q4 * 4 + r;
          int srcc = li + 15 - il;                    // 0..30
          int lsrc = (lane & 48) | (srcc & 15);
          float g0 = __shfl(accG[nt][r], lsrc);
          float g1 = __shfl(accG[nt + 1][r], lsrc);
          float g = (srcc < 16) ? g0 : g1;
          float s = (accS[nt][r] + g) * SCALEF;
          if (j0 + nt * 16 + li > i0 + w * 16 + il) s = NEGF;
          Sv[nt][r] = s;
        }
      float mnew[4], alpha[4], psum[4];
#pragma unroll
      for (int r = 0; r < 4; ++r) {
        float mx = fmaxf(fmaxf(Sv[0][r], Sv[1][r]), fmaxf(Sv[2][r], Sv[3][r]));
        mx = fmaxf(mx, __shfl_xor(mx, 1));
        mx = fmaxf(mx, __shfl_xor(mx, 2));
        mx = fmaxf(mx, __shfl_xor(mx, 4));
        mx = fmaxf(mx, __shfl_xor(mx, 8));
        mnew[r] = fmaxf(mst[r], mx);
        alpha[r] = __expf(mst[r] - mnew[r]);
        psum[r] = 0.f;
      }
#pragma unroll
      for (int nt = 0; nt < 4; ++nt)
#pragma unroll
        for (int r = 0; r < 4; ++r) {
          float pv = __expf(Sv[nt][r] - mnew[r]);
          psum[r] += pv;
          sP[w][q4 * 4 + r][nt * 16 + li] = f2b(pv);
        }
#pragma unroll
      for (int r = 0; r < 4; ++r) {
        float ps = psum[r];
        ps += __shfl_xor(ps, 1);
        ps += __shfl_xor(ps, 2);
        ps += __shfl_xor(ps, 4);
        ps += __shfl_xor(ps, 8);
        lst[r] = lst[r] * alpha[r] + ps;
        mst[r] = mnew[r];
      }
#pragma unroll
      for (int nt = 0; nt < 4; ++nt) {
        f32x4 o = accO[nt];
#pragma unroll
        for (int r = 0; r < 4; ++r) o[r] *= alpha[r];
        accO[nt] = o;
      }
      // PV: sP is per-wave private -> no barrier needed before reading it
#pragma unroll
      for (int kc = 0; kc < 2; ++kc) {
        bf16x8 ap = *(const bf16x8*)&sP[w][li][kc * 32 + q4 * 8];
#pragma unroll
        for (int nt = 0; nt < 4; ++nt) {
          bf16x8 fv = *(const bf16x8*)&sVt[nt * 16 + li][kc * 32 + q4 * 8];
          accO[nt] = MFMA(ap, fv, accO[nt]);
        }
      }
      __syncthreads();
    }
#pragma unroll
    for (int r = 0; r < 4; ++r) {
      int il = q4 * 4 + r;
      int ig = i0 + w * 16 + il;
      float inv = 1.0f / lst[r];
      u16* orow = vec + (((size_t)ig * 4 + b) * 16 + n) * 64;
#pragma unroll
      for (int nt = 0; nt < 4; ++nt) orow[nt * 16 + li] = f2b(accO[nt][r] * inv);
    }
  }
}

// ---------------- residual + layernorm ----------------
__global__ __launch_bounds__(256) void resid_ln(const float* __restrict__ w,
                                                const float* __restrict__ attn,
                                                const float* __restrict__ gamma,
                                                const float* __restrict__ beta,
                                                float* __restrict__ out) {
  __shared__ float ssum[4], ssq[4];
  int row = blockIdx.x, t = threadIdx.x;
  float4 xw = *(const float4*)&w[(size_t)row * 1024 + t * 4];
  float4 xa = *(const float4*)&attn[(size_t)row * 1024 + t * 4];
  float4 x = make_float4(xw.x + xa.x, xw.y + xa.y, xw.z + xa.z, xw.w + xa.w);
  float s = x.x + x.y + x.z + x.w;
  float sq = x.x * x.x + x.y * x.y + x.z * x.z + x.w * x.w;
#pragma unroll
  for (int off = 32; off > 0; off >>= 1) {
    s += __shfl_down(s, off);
    sq += __shfl_down(sq, off);
  }
  int wid = t >> 6;
  if ((t & 63) == 0) { ssum[wid] = s; ssq[wid] = sq; }
  __syncthreads();
  s = ssum[0] + ssum[1] + ssum[2] + ssum[3];
  sq = ssq[0] + ssq[1] + ssq[2] + ssq[3];
  float mean = s * (1.0f / 1024.0f);
  float var = sq * (1.0f / 1024.0f) - mean * mean;
  float rstd = rsqrtf(var + 1e-5f);
  float4 g = *(const float4*)&gamma[t * 4];
  float4 bb = *(const float4*)&beta[t * 4];
  float4 o;
  o.x = (x.x - mean) * rstd * g.x + bb.x;
  o.y = (x.y - mean) * rstd * g.y + bb.y;
  o.z = (x.z - mean) * rstd * g.z + bb.z;
  o.w = (x.w - mean) * rstd * g.w + bb.w;
  *(float4*)&out[(size_t)row * 1024 + t * 4] = o;
}

extern "C" void kernel_launch(void* const* d_in, const int* in_sizes, int n_in,
                              void* d_out, int out_size, void* d_ws, size_t ws_size,
                              hipStream_t stream) {
  const float* w     = (const float*)d_in[0];
  const float* r     = (const float*)d_in[1];
  const float* rwb   = (const float*)d_in[2];
  const float* rrb   = (const float*)d_in[3];
  const float* W_qkv = (const float*)d_in[4];
  const float* W_r   = (const float*)d_in[5];
  const float* W_o   = (const float*)d_in[6];
  const float* cwq   = (const float*)d_in[7];
  const float* cbq   = (const float*)d_in[8];
  const float* cwk   = (const float*)d_in[9];
  const float* cbk   = (const float*)d_in[10];
  const float* cwv   = (const float*)d_in[11];
  const float* cbv   = (const float*)d_in[12];
  const float* gamma = (const float*)d_in[13];
  const float* beta  = (const float*)d_in[14];
  float* outp = (float*)d_out;

  char* wsb = (char*)d_ws;
  u16*   heads   = (u16*)(wsb);                 // [4096][3072] bf16 = 24 MB
  u16*   vec     = (u16*)(wsb);                 // alias (heads dead after convs): 8 MB
  float* attnf   = (float*)(wsb + 8388608);     // 16 MB (within dead heads region)
  u16*   qh      = (u16*)(wsb + 25165824);      // 8 MB
  u16*   kh      = (u16*)(wsb + 33554432);      // 8 MB
  u16*   rhk     = (u16*)(wsb + 50331648);      // 2 MB
  u16*   w_bf    = (u16*)(wsb + 52428800);
  u16*   wqkv_bf = (u16*)(wsb + 60817408);
  u16*   r_bf    = (u16*)(wsb + 67108864);
  u16*   wr_bf   = (u16*)(wsb + 69206016);
  u16*   wo_bf   = (u16*)(wsb + 71303168);
  u16*   wTq     = (u16*)(wsb + 73400320);
  u16*   wTk     = (u16*)(wsb + 73457664);
  u16*   wTv     = (u16*)(wsb + 73515008);
  u16*   vt      = (u16*)(wsb + 73572352);      // [64][64][1024] bf16 = 8 MB

  dim3 blk(256);
  prep<<<10576, blk, 0, stream>>>(w, W_qkv, r, W_r, W_o, cwq, cwk, cwv,
                                  w_bf, wqkv_bf, r_bf, wr_bf, wo_bf, wTq, wTk, wTv);
  gemm_stage1<<<832, blk, 0, stream>>>(w_bf, wqkv_bf, heads, r_bf, wr_bf, rhk);
  conv3<<<dim3(16, 64, 3), blk, 0, stream>>>(heads, wTq, wTk, wTv, cbq, cbk, cbv, qh, kh, vt);
  rel_attn<<<dim3(8, 64), blk, 0, stream>>>(qh, kh, vt, rhk, rwb, rrb, vec);
  gemm_wo<<<dim3(8, 32), blk, 0, stream>>>(vec, wo_bf, attnf);
  resid_ln<<<4096, blk, 0, stream>>>(w, attnf, gamma, beta, outp);
}